// Round 1
// baseline (254.529 us; speedup 1.0000x reference)
//
#include <hip/hip_runtime.h>
#include <stdint.h>

typedef unsigned short u16;
typedef unsigned int u32;
typedef __bf16 bf16x8 __attribute__((ext_vector_type(8)));
typedef float f32x4 __attribute__((ext_vector_type(4)));

#define NH 12
#define HD 64
#define SEQ 512
#define BATCH 16
#define HID 768
#define SCALE_Q 0.03608439182435161f  // 768^-0.5

__device__ __forceinline__ u16 f2bf(float f) {
    u32 u = __builtin_bit_cast(u32, f);
    u32 r = (u + 0x7FFFu + ((u >> 16) & 1u)) >> 16;
    return (u16)r;
}

// ---------------- fp32 -> bf16 convert ----------------
__global__ void cvt_kernel(const float* __restrict__ src, u16* __restrict__ dst, int n4) {
    int i = (blockIdx.x * 256 + threadIdx.x) * 4;
    float4 v = *(const float4*)(src + i);
    ushort4 o;
    o.x = f2bf(v.x); o.y = f2bf(v.y); o.z = f2bf(v.z); o.w = f2bf(v.w);
    *(ushort4*)(dst + i) = o;
    (void)n4;
}

// ---------------- NT GEMM: C[M,768] = A[M,768] * W[768,768]^T ----------------
// MODE 0: write bf16 to [b,h,n,d]   (q / k)
// MODE 2: write bf16 to [b,h,d,m] transposed, + bias (v)
// MODE 3: write fp32 row-major + bias (final out)
#define LDK 40

template <int MODE>
__global__ __launch_bounds__(256, 2) void gemm_nt(
    const u16* __restrict__ A, const u16* __restrict__ Bw,
    const float* __restrict__ bias, void* __restrict__ Cout)
{
    __shared__ __align__(16) u16 As[128 * LDK];
    __shared__ __align__(16) u16 Bs[128 * LDK];
    const int tid = threadIdx.x;
    const int l = tid & 63, w = tid >> 6;
    const int wm = w & 1, wn = w >> 1;
    const int lr = l & 15, lg = l >> 4;
    const int mt = blockIdx.x, nt = blockIdx.y;

    const int row0 = tid >> 2;       // staging: 4 lanes per row, 16B each
    const int k8 = (tid & 3) * 8;

    const u16* Ag = A + (size_t)(mt * 128) * HID;
    const u16* Bg = Bw + (size_t)(nt * 128) * HID;

    f32x4 acc[4][4] = {};

    for (int k0 = 0; k0 < HID; k0 += 32) {
        uint4 a0 = *(const uint4*)(Ag + (size_t)row0 * HID + k0 + k8);
        uint4 a1 = *(const uint4*)(Ag + (size_t)(row0 + 64) * HID + k0 + k8);
        uint4 b0 = *(const uint4*)(Bg + (size_t)row0 * HID + k0 + k8);
        uint4 b1 = *(const uint4*)(Bg + (size_t)(row0 + 64) * HID + k0 + k8);
        __syncthreads();
        *(uint4*)(As + row0 * LDK + k8) = a0;
        *(uint4*)(As + (row0 + 64) * LDK + k8) = a1;
        *(uint4*)(Bs + row0 * LDK + k8) = b0;
        *(uint4*)(Bs + (row0 + 64) * LDK + k8) = b1;
        __syncthreads();

        bf16x8 af[4], bfr[4];
#pragma unroll
        for (int mi = 0; mi < 4; mi++)
            af[mi] = *(const bf16x8*)(As + (wm * 64 + mi * 16 + lr) * LDK + lg * 8);
#pragma unroll
        for (int ni = 0; ni < 4; ni++)
            bfr[ni] = *(const bf16x8*)(Bs + (wn * 64 + ni * 16 + lr) * LDK + lg * 8);
#pragma unroll
        for (int mi = 0; mi < 4; mi++)
#pragma unroll
            for (int ni = 0; ni < 4; ni++)
                acc[mi][ni] = __builtin_amdgcn_mfma_f32_16x16x32_bf16(af[mi], bfr[ni], acc[mi][ni], 0, 0, 0);
    }

#pragma unroll
    for (int mi = 0; mi < 4; mi++) {
#pragma unroll
        for (int ni = 0; ni < 4; ni++) {
            const int jg = nt * 128 + wn * 64 + ni * 16 + lr;
            if constexpr (MODE == 3) {
                float bb = bias[jg];
                float* O = (float*)Cout;
#pragma unroll
                for (int r = 0; r < 4; r++) {
                    int ig = mt * 128 + wm * 64 + mi * 16 + lg * 4 + r;
                    O[(size_t)ig * HID + jg] = acc[mi][ni][r] + bb;
                }
            } else if constexpr (MODE == 2) {
                float bb = bias[jg];
                int h = jg >> 6, d = jg & 63;
                int i0 = mt * 128 + wm * 64 + mi * 16 + lg * 4;
                int b = i0 >> 9, m = i0 & 511;
                ushort4 pk;
                pk.x = f2bf(acc[mi][ni][0] + bb);
                pk.y = f2bf(acc[mi][ni][1] + bb);
                pk.z = f2bf(acc[mi][ni][2] + bb);
                pk.w = f2bf(acc[mi][ni][3] + bb);
                u16* O = (u16*)Cout;
                *(ushort4*)(O + ((size_t)(b * NH + h) * HD + d) * SEQ + m) = pk;
            } else {
                int h = jg >> 6, d = jg & 63;
                u16* O = (u16*)Cout;
#pragma unroll
                for (int r = 0; r < 4; r++) {
                    int ig = mt * 128 + wm * 64 + mi * 16 + lg * 4 + r;
                    int b = ig >> 9, n = ig & 511;
                    O[((size_t)(b * NH + h) * SEQ + n) * HD + d] = f2bf(acc[mi][ni][r]);
                }
            }
        }
    }
}

// ---------------- fused flash attention ----------------
// grid (8 qtiles, 12 heads, 16 batch), 256 threads; wave w owns q rows [qt*64+w*16, +16)
#define LDA 88

__global__ __launch_bounds__(256, 2) void attn_kernel(
    const u16* __restrict__ qb, const u16* __restrict__ kb, const u16* __restrict__ vtb,
    const float* __restrict__ eb, u16* __restrict__ ob)
{
    __shared__ __align__(16) u16 Ks[64 * LDA];
    __shared__ __align__(16) u16 Vs[64 * LDA];
    __shared__ __align__(16) u16 Ps[4][16 * LDA];

    const int tid = threadIdx.x;
    const int l = tid & 63, w = tid >> 6;
    const int lr = l & 15, lg = l >> 4;
    const int qt = blockIdx.x, h = blockIdx.y, b = blockIdx.z;
    const int bh = b * NH + h;
    const int qrow0 = qt * 64 + w * 16;

    // Q fragments (A-layout), kept in registers for the whole kernel
    const u16* qptr = qb + ((size_t)bh * SEQ + qrow0 + lr) * HD;
    bf16x8 qf0 = *(const bf16x8*)(qptr + lg * 8);
    bf16x8 qf1 = *(const bf16x8*)(qptr + 32 + lg * 8);

    const u16* Kg = kb + (size_t)bh * SEQ * HD;
    const u16* Vg = vtb + (size_t)bh * HD * SEQ;
    const float* Eg = eb + ((size_t)b * SEQ + qrow0 + lg * 4) * SEQ;

    f32x4 oacc[4] = {};
    float run_m[4] = {-1e30f, -1e30f, -1e30f, -1e30f};
    float run_l[4] = {0.f, 0.f, 0.f, 0.f};
    int nzf[4] = {0, 0, 0, 0};

    const int c0 = tid, c1 = tid + 256;  // staging chunk ids (512 x 16B per tile)

    for (int mt0 = 0; mt0 < SEQ; mt0 += 64) {
        uint4 kv0 = *(const uint4*)(Kg + (size_t)(mt0 + (c0 >> 3)) * HD + (c0 & 7) * 8);
        uint4 kv1 = *(const uint4*)(Kg + (size_t)(mt0 + (c1 >> 3)) * HD + (c1 & 7) * 8);
        uint4 vv0 = *(const uint4*)(Vg + (size_t)(c0 >> 3) * SEQ + mt0 + (c0 & 7) * 8);
        uint4 vv1 = *(const uint4*)(Vg + (size_t)(c1 >> 3) * SEQ + mt0 + (c1 & 7) * 8);
        __syncthreads();
        *(uint4*)(Ks + (c0 >> 3) * LDA + (c0 & 7) * 8) = kv0;
        *(uint4*)(Ks + (c1 >> 3) * LDA + (c1 & 7) * 8) = kv1;
        *(uint4*)(Vs + (c0 >> 3) * LDA + (c0 & 7) * 8) = vv0;
        *(uint4*)(Vs + (c1 >> 3) * LDA + (c1 & 7) * 8) = vv1;
        __syncthreads();

        // S = Q K^T * SCALE + bias ; S subtile [16 q-rows x 64 m]
        float sm[4][4];
#pragma unroll
        for (int mi = 0; mi < 4; mi++) {
            bf16x8 kf0 = *(const bf16x8*)(Ks + (mi * 16 + lr) * LDA + lg * 8);
            bf16x8 kf1 = *(const bf16x8*)(Ks + (mi * 16 + lr) * LDA + 32 + lg * 8);
            f32x4 s = {};
            s = __builtin_amdgcn_mfma_f32_16x16x32_bf16(qf0, kf0, s, 0, 0, 0);
            s = __builtin_amdgcn_mfma_f32_16x16x32_bf16(qf1, kf1, s, 0, 0, 0);
#pragma unroll
            for (int r = 0; r < 4; r++) {
                float sv = s[r] * SCALE_Q + Eg[(size_t)r * SEQ + mt0 + mi * 16 + lr];
                nzf[r] |= (sv != 0.0f);
                sm[mi][r] = sv;
            }
        }

        // online softmax (row state replicated across the 16-lane col group)
        u16* Pw = Ps[w];
#pragma unroll
        for (int r = 0; r < 4; r++) {
            float tm = fmaxf(fmaxf(sm[0][r], sm[1][r]), fmaxf(sm[2][r], sm[3][r]));
            tm = fmaxf(tm, __shfl_xor(tm, 1));
            tm = fmaxf(tm, __shfl_xor(tm, 2));
            tm = fmaxf(tm, __shfl_xor(tm, 4));
            tm = fmaxf(tm, __shfl_xor(tm, 8));
            float nm = fmaxf(run_m[r], tm);
            float alpha = __expf(run_m[r] - nm);
            run_m[r] = nm;
            float ps = 0.f;
#pragma unroll
            for (int mi = 0; mi < 4; mi++) {
                float p = __expf(sm[mi][r] - nm);
                sm[mi][r] = p;
                ps += p;
            }
            ps += __shfl_xor(ps, 1);
            ps += __shfl_xor(ps, 2);
            ps += __shfl_xor(ps, 4);
            ps += __shfl_xor(ps, 8);
            run_l[r] = run_l[r] * alpha + ps;
#pragma unroll
            for (int di = 0; di < 4; di++) oacc[di][r] *= alpha;
        }
        // P: C-layout -> LDS -> A-layout (per-wave region, no barrier needed)
#pragma unroll
        for (int mi = 0; mi < 4; mi++)
#pragma unroll
            for (int r = 0; r < 4; r++)
                Pw[(lg * 4 + r) * LDA + mi * 16 + lr] = f2bf(sm[mi][r]);

#pragma unroll
        for (int ks = 0; ks < 2; ks++) {
            bf16x8 pf = *(const bf16x8*)(Pw + lr * LDA + ks * 32 + lg * 8);
#pragma unroll
            for (int di = 0; di < 4; di++) {
                bf16x8 vf = *(const bf16x8*)(Vs + (di * 16 + lr) * LDA + ks * 32 + lg * 8);
                oacc[di] = __builtin_amdgcn_mfma_f32_16x16x32_bf16(pf, vf, oacc[di], 0, 0, 0);
            }
        }
    }

#pragma unroll
    for (int r = 0; r < 4; r++) {
        int nz = nzf[r];
        nz |= __shfl_xor(nz, 1);
        nz |= __shfl_xor(nz, 2);
        nz |= __shfl_xor(nz, 4);
        nz |= __shfl_xor(nz, 8);
        float inv = nz ? (1.0f / run_l[r]) : 0.0f;  // all-zero row -> output 0 (ref: softmax NaN -> 0)
        int n = qrow0 + lg * 4 + r;
        u16* orow = ob + ((size_t)b * SEQ + n) * HID + h * HD;
#pragma unroll
        for (int di = 0; di < 4; di++)
            orow[di * 16 + lr] = f2bf(oacc[di][r] * inv);
    }
}

// ---------------- launch ----------------
extern "C" void kernel_launch(void* const* d_in, const int* in_sizes, int n_in,
                              void* d_out, int out_size, void* d_ws, size_t ws_size,
                              hipStream_t stream) {
    (void)in_sizes; (void)n_in; (void)out_size; (void)ws_size;
    const float* x  = (const float*)d_in[0];
    const float* eb = (const float*)d_in[1];
    const float* Wq = (const float*)d_in[2];
    const float* Wk = (const float*)d_in[3];
    const float* Wv = (const float*)d_in[4];
    const float* bv = (const float*)d_in[5];
    const float* Wo = (const float*)d_in[6];
    const float* bo = (const float*)d_in[7];
    float* out = (float*)d_out;

    const int NX = BATCH * SEQ * HID;  // 6291456
    const int NW = HID * HID;          // 589824
    u16* ws   = (u16*)d_ws;
    u16* xb   = ws;
    u16* wqb  = xb + NX;
    u16* wkb  = wqb + NW;
    u16* wvb  = wkb + NW;
    u16* wob  = wvb + NW;
    u16* qb   = wob + NW;
    u16* kb   = qb + NX;
    u16* vtb  = kb + NX;
    u16* obuf = vtb + NX;

    cvt_kernel<<<NX / 1024, 256, 0, stream>>>(x, xb, NX / 4);
    cvt_kernel<<<NW / 1024, 256, 0, stream>>>(Wq, wqb, NW / 4);
    cvt_kernel<<<NW / 1024, 256, 0, stream>>>(Wk, wkb, NW / 4);
    cvt_kernel<<<NW / 1024, 256, 0, stream>>>(Wv, wvb, NW / 4);
    cvt_kernel<<<NW / 1024, 256, 0, stream>>>(Wo, wob, NW / 4);

    dim3 gg(64, 6);
    gemm_nt<0><<<gg, 256, 0, stream>>>(xb, wqb, nullptr, qb);
    gemm_nt<0><<<gg, 256, 0, stream>>>(xb, wkb, nullptr, kb);
    gemm_nt<2><<<gg, 256, 0, stream>>>(xb, wvb, bv, vtb);

    attn_kernel<<<dim3(8, NH, BATCH), 256, 0, stream>>>(qb, kb, vtb, eb, obuf);

    gemm_nt<3><<<gg, 256, 0, stream>>>(obuf, wob, bo, out);
}

// Round 2
// 230.369 us; speedup vs baseline: 1.1049x; 1.1049x over previous
//
#include <hip/hip_runtime.h>
#include <stdint.h>

typedef unsigned short u16;
typedef unsigned int u32;
typedef __bf16 bf16x8 __attribute__((ext_vector_type(8)));
typedef float f32x4 __attribute__((ext_vector_type(4)));

#define NH 12
#define HD 64
#define SEQ 512
#define BATCH 16
#define HID 768
#define SCALE_Q 0.03608439182435161f  // 768^-0.5

__device__ __forceinline__ u16 f2bf(float f) {
    u32 u = __builtin_bit_cast(u32, f);
    u32 r = (u + 0x7FFFu + ((u >> 16) & 1u)) >> 16;
    return (u16)r;
}

// async global -> LDS, 16B per lane; lds dest = wave-uniform base + lane*16
__device__ __forceinline__ void gl2lds16(const u16* g, u16* lds_base) {
    __builtin_amdgcn_global_load_lds(
        (const __attribute__((address_space(1))) u32*)g,
        (__attribute__((address_space(3))) u32*)lds_base, 16, 0, 0);
}

// ---------------- fp32 -> bf16 converts ----------------
__global__ void cvt_kernel(const float* __restrict__ src, u16* __restrict__ dst) {
    int i = (blockIdx.x * 256 + threadIdx.x) * 4;
    float4 v = *(const float4*)(src + i);
    ushort4 o;
    o.x = f2bf(v.x); o.y = f2bf(v.y); o.z = f2bf(v.z); o.w = f2bf(v.w);
    *(ushort4*)(dst + i) = o;
}

__global__ void cvt4_kernel(const float* __restrict__ s0, const float* __restrict__ s1,
                            const float* __restrict__ s2, const float* __restrict__ s3,
                            u16* __restrict__ d0, u16* __restrict__ d1,
                            u16* __restrict__ d2, u16* __restrict__ d3) {
    int y = blockIdx.y;
    const float* s = (y == 0) ? s0 : (y == 1) ? s1 : (y == 2) ? s2 : s3;
    u16* d = (y == 0) ? d0 : (y == 1) ? d1 : (y == 2) ? d2 : d3;
    int i = (blockIdx.x * 256 + threadIdx.x) * 4;
    float4 v = *(const float4*)(s + i);
    ushort4 o;
    o.x = f2bf(v.x); o.y = f2bf(v.y); o.z = f2bf(v.z); o.w = f2bf(v.w);
    *(ushort4*)(d + i) = o;
}

// ---------------- m97-structure NT GEMM mainloop ----------------
// C[128,128] tile = A[128,768] * W[128,768]^T, BK=32, unpadded LDS [128][32],
// staging via global_load_lds dwordx4 (lane-contiguous chunks, 2-barrier K-loop)
__device__ __forceinline__ void gemm_mainloop(
    const u16* __restrict__ Ag, const u16* __restrict__ Bg,
    u16* As, u16* Bs, f32x4 (&acc)[4][4])
{
    const int tid = threadIdx.x;
    const int l = tid & 63, w = tid >> 6;
    const int wm = w & 1, wn = w >> 1;
    const int lr = l & 15, lg = l >> 4;

    // chunk c in [0,512): row = c>>2, col8 = (c&3)*8; LDS byte off = c*16
    const int c0 = tid, c1 = tid + 256;
    const int r0 = c0 >> 2, q0 = (c0 & 3) * 8;
    const int r1 = c1 >> 2, q1 = (c1 & 3) * 8;
    u16* Alds0 = As + w * 512;            // chunk group w*64, bytes w*1024
    u16* Alds1 = As + 2048 + w * 512;
    u16* Blds0 = Bs + w * 512;
    u16* Blds1 = Bs + 2048 + w * 512;

    for (int k0 = 0; k0 < HID; k0 += 32) {
        __syncthreads();  // prev iteration's ds_reads done before overwrite
        gl2lds16(Ag + (size_t)r0 * HID + k0 + q0, Alds0);
        gl2lds16(Ag + (size_t)r1 * HID + k0 + q1, Alds1);
        gl2lds16(Bg + (size_t)r0 * HID + k0 + q0, Blds0);
        gl2lds16(Bg + (size_t)r1 * HID + k0 + q1, Blds1);
        __syncthreads();  // drains vmcnt -> LDS tiles complete

        bf16x8 af[4], bfr[4];
#pragma unroll
        for (int mi = 0; mi < 4; mi++)
            af[mi] = *(const bf16x8*)(As + (wm * 64 + mi * 16 + lr) * 32 + lg * 8);
#pragma unroll
        for (int ni = 0; ni < 4; ni++)
            bfr[ni] = *(const bf16x8*)(Bs + (wn * 64 + ni * 16 + lr) * 32 + lg * 8);
#pragma unroll
        for (int mi = 0; mi < 4; mi++)
#pragma unroll
            for (int ni = 0; ni < 4; ni++)
                acc[mi][ni] = __builtin_amdgcn_mfma_f32_16x16x32_bf16(af[mi], bfr[ni], acc[mi][ni], 0, 0, 0);
    }
}

// ---------------- fused QKV GEMM: grid.z selects {Wq,Wk,Wv} ----------------
__global__ __launch_bounds__(256, 2) void gemm_qkv(
    const u16* __restrict__ xb, const u16* __restrict__ wq,
    const u16* __restrict__ wk, const u16* __restrict__ wv,
    const float* __restrict__ bv,
    u16* __restrict__ qb, u16* __restrict__ kb, u16* __restrict__ vtb)
{
    __shared__ __align__(16) u16 As[128 * 32];
    __shared__ __align__(16) u16 Bs[128 * 32];
    const int tid = threadIdx.x;
    const int l = tid & 63, w = tid >> 6;
    const int wm = w & 1, wn = w >> 1;
    const int lr = l & 15, lg = l >> 4;
    const int mt = blockIdx.x, nt = blockIdx.y, z = blockIdx.z;

    const u16* Bw = (z == 0) ? wq : (z == 1) ? wk : wv;
    const u16* Ag = xb + (size_t)(mt * 128) * HID;
    const u16* Bg = Bw + (size_t)(nt * 128) * HID;

    f32x4 acc[4][4] = {};
    gemm_mainloop(Ag, Bg, As, Bs, acc);

#pragma unroll
    for (int mi = 0; mi < 4; mi++) {
#pragma unroll
        for (int ni = 0; ni < 4; ni++) {
            const int jg = nt * 128 + wn * 64 + ni * 16 + lr;
            const int h = jg >> 6, d = jg & 63;
            if (z < 2) {
                u16* O = (z == 0) ? qb : kb;  // [b,h,n,d]
#pragma unroll
                for (int r = 0; r < 4; r++) {
                    int ig = mt * 128 + wm * 64 + mi * 16 + lg * 4 + r;
                    int b = ig >> 9, n = ig & 511;
                    O[((size_t)(b * NH + h) * SEQ + n) * HD + d] = f2bf(acc[mi][ni][r]);
                }
            } else {                           // v: [b,h,d,m] transposed, + bias
                float bb = bv[jg];
                int i0 = mt * 128 + wm * 64 + mi * 16 + lg * 4;
                int b = i0 >> 9, m = i0 & 511;
                ushort4 pk;
                pk.x = f2bf(acc[mi][ni][0] + bb);
                pk.y = f2bf(acc[mi][ni][1] + bb);
                pk.z = f2bf(acc[mi][ni][2] + bb);
                pk.w = f2bf(acc[mi][ni][3] + bb);
                *(ushort4*)(vtb + ((size_t)(b * NH + h) * HD + d) * SEQ + m) = pk;
            }
        }
    }
}

// ---------------- output GEMM: fp32 out + bias ----------------
__global__ __launch_bounds__(256, 2) void gemm_out(
    const u16* __restrict__ A, const u16* __restrict__ wo,
    const float* __restrict__ bo, float* __restrict__ Cout)
{
    __shared__ __align__(16) u16 As[128 * 32];
    __shared__ __align__(16) u16 Bs[128 * 32];
    const int tid = threadIdx.x;
    const int l = tid & 63, w = tid >> 6;
    const int wm = w & 1, wn = w >> 1;
    const int lr = l & 15, lg = l >> 4;
    const int mt = blockIdx.x, nt = blockIdx.y;

    const u16* Ag = A + (size_t)(mt * 128) * HID;
    const u16* Bg = wo + (size_t)(nt * 128) * HID;

    f32x4 acc[4][4] = {};
    gemm_mainloop(Ag, Bg, As, Bs, acc);

#pragma unroll
    for (int mi = 0; mi < 4; mi++) {
#pragma unroll
        for (int ni = 0; ni < 4; ni++) {
            const int jg = nt * 128 + wn * 64 + ni * 16 + lr;
            float bb = bo[jg];
#pragma unroll
            for (int r = 0; r < 4; r++) {
                int ig = mt * 128 + wm * 64 + mi * 16 + lg * 4 + r;
                Cout[(size_t)ig * HID + jg] = acc[mi][ni][r] + bb;
            }
        }
    }
}

// ---------------- fused flash attention (unchanged from R1) ----------------
#define LDA 88

__global__ __launch_bounds__(256, 2) void attn_kernel(
    const u16* __restrict__ qb, const u16* __restrict__ kb, const u16* __restrict__ vtb,
    const float* __restrict__ eb, u16* __restrict__ ob)
{
    __shared__ __align__(16) u16 Ks[64 * LDA];
    __shared__ __align__(16) u16 Vs[64 * LDA];
    __shared__ __align__(16) u16 Ps[4][16 * LDA];

    const int tid = threadIdx.x;
    const int l = tid & 63, w = tid >> 6;
    const int lr = l & 15, lg = l >> 4;
    const int qt = blockIdx.x, h = blockIdx.y, b = blockIdx.z;
    const int bh = b * NH + h;
    const int qrow0 = qt * 64 + w * 16;

    const u16* qptr = qb + ((size_t)bh * SEQ + qrow0 + lr) * HD;
    bf16x8 qf0 = *(const bf16x8*)(qptr + lg * 8);
    bf16x8 qf1 = *(const bf16x8*)(qptr + 32 + lg * 8);

    const u16* Kg = kb + (size_t)bh * SEQ * HD;
    const u16* Vg = vtb + (size_t)bh * HD * SEQ;
    const float* Eg = eb + ((size_t)b * SEQ + qrow0 + lg * 4) * SEQ;

    f32x4 oacc[4] = {};
    float run_m[4] = {-1e30f, -1e30f, -1e30f, -1e30f};
    float run_l[4] = {0.f, 0.f, 0.f, 0.f};
    int nzf[4] = {0, 0, 0, 0};

    const int c0 = tid, c1 = tid + 256;

    for (int mt0 = 0; mt0 < SEQ; mt0 += 64) {
        uint4 kv0 = *(const uint4*)(Kg + (size_t)(mt0 + (c0 >> 3)) * HD + (c0 & 7) * 8);
        uint4 kv1 = *(const uint4*)(Kg + (size_t)(mt0 + (c1 >> 3)) * HD + (c1 & 7) * 8);
        uint4 vv0 = *(const uint4*)(Vg + (size_t)(c0 >> 3) * SEQ + mt0 + (c0 & 7) * 8);
        uint4 vv1 = *(const uint4*)(Vg + (size_t)(c1 >> 3) * SEQ + mt0 + (c1 & 7) * 8);
        __syncthreads();
        *(uint4*)(Ks + (c0 >> 3) * LDA + (c0 & 7) * 8) = kv0;
        *(uint4*)(Ks + (c1 >> 3) * LDA + (c1 & 7) * 8) = kv1;
        *(uint4*)(Vs + (c0 >> 3) * LDA + (c0 & 7) * 8) = vv0;
        *(uint4*)(Vs + (c1 >> 3) * LDA + (c1 & 7) * 8) = vv1;
        __syncthreads();

        float sm[4][4];
#pragma unroll
        for (int mi = 0; mi < 4; mi++) {
            bf16x8 kf0 = *(const bf16x8*)(Ks + (mi * 16 + lr) * LDA + lg * 8);
            bf16x8 kf1 = *(const bf16x8*)(Ks + (mi * 16 + lr) * LDA + 32 + lg * 8);
            f32x4 s = {};
            s = __builtin_amdgcn_mfma_f32_16x16x32_bf16(qf0, kf0, s, 0, 0, 0);
            s = __builtin_amdgcn_mfma_f32_16x16x32_bf16(qf1, kf1, s, 0, 0, 0);
#pragma unroll
            for (int r = 0; r < 4; r++) {
                float sv = s[r] * SCALE_Q + Eg[(size_t)r * SEQ + mt0 + mi * 16 + lr];
                nzf[r] |= (sv != 0.0f);
                sm[mi][r] = sv;
            }
        }

        u16* Pw = Ps[w];
#pragma unroll
        for (int r = 0; r < 4; r++) {
            float tm = fmaxf(fmaxf(sm[0][r], sm[1][r]), fmaxf(sm[2][r], sm[3][r]));
            tm = fmaxf(tm, __shfl_xor(tm, 1));
            tm = fmaxf(tm, __shfl_xor(tm, 2));
            tm = fmaxf(tm, __shfl_xor(tm, 4));
            tm = fmaxf(tm, __shfl_xor(tm, 8));
            float nm = fmaxf(run_m[r], tm);
            float alpha = __expf(run_m[r] - nm);
            run_m[r] = nm;
            float ps = 0.f;
#pragma unroll
            for (int mi = 0; mi < 4; mi++) {
                float p = __expf(sm[mi][r] - nm);
                sm[mi][r] = p;
                ps += p;
            }
            ps += __shfl_xor(ps, 1);
            ps += __shfl_xor(ps, 2);
            ps += __shfl_xor(ps, 4);
            ps += __shfl_xor(ps, 8);
            run_l[r] = run_l[r] * alpha + ps;
#pragma unroll
            for (int di = 0; di < 4; di++) oacc[di][r] *= alpha;
        }
#pragma unroll
        for (int mi = 0; mi < 4; mi++)
#pragma unroll
            for (int r = 0; r < 4; r++)
                Pw[(lg * 4 + r) * LDA + mi * 16 + lr] = f2bf(sm[mi][r]);

#pragma unroll
        for (int ks = 0; ks < 2; ks++) {
            bf16x8 pf = *(const bf16x8*)(Pw + lr * LDA + ks * 32 + lg * 8);
#pragma unroll
            for (int di = 0; di < 4; di++) {
                bf16x8 vf = *(const bf16x8*)(Vs + (di * 16 + lr) * LDA + ks * 32 + lg * 8);
                oacc[di] = __builtin_amdgcn_mfma_f32_16x16x32_bf16(pf, vf, oacc[di], 0, 0, 0);
            }
        }
    }

#pragma unroll
    for (int r = 0; r < 4; r++) {
        int nz = nzf[r];
        nz |= __shfl_xor(nz, 1);
        nz |= __shfl_xor(nz, 2);
        nz |= __shfl_xor(nz, 4);
        nz |= __shfl_xor(nz, 8);
        float inv = nz ? (1.0f / run_l[r]) : 0.0f;
        int n = qrow0 + lg * 4 + r;
        u16* orow = ob + ((size_t)b * SEQ + n) * HID + h * HD;
#pragma unroll
        for (int di = 0; di < 4; di++)
            orow[di * 16 + lr] = f2bf(oacc[di][r] * inv);
    }
}

// ---------------- launch ----------------
extern "C" void kernel_launch(void* const* d_in, const int* in_sizes, int n_in,
                              void* d_out, int out_size, void* d_ws, size_t ws_size,
                              hipStream_t stream) {
    (void)in_sizes; (void)n_in; (void)out_size; (void)ws_size;
    const float* x  = (const float*)d_in[0];
    const float* eb = (const float*)d_in[1];
    const float* Wq = (const float*)d_in[2];
    const float* Wk = (const float*)d_in[3];
    const float* Wv = (const float*)d_in[4];
    const float* bv = (const float*)d_in[5];
    const float* Wo = (const float*)d_in[6];
    const float* bo = (const float*)d_in[7];
    float* out = (float*)d_out;

    const int NX = BATCH * SEQ * HID;  // 6291456
    const int NW = HID * HID;          // 589824
    u16* ws   = (u16*)d_ws;
    u16* xb   = ws;
    u16* wqb  = xb + NX;
    u16* wkb  = wqb + NW;
    u16* wvb  = wkb + NW;
    u16* wob  = wvb + NW;
    u16* qb   = wob + NW;
    u16* kb   = qb + NX;
    u16* vtb  = kb + NX;
    u16* obuf = vtb + NX;

    cvt_kernel<<<NX / 1024, 256, 0, stream>>>(x, xb);
    cvt4_kernel<<<dim3(NW / 1024, 4), 256, 0, stream>>>(Wq, Wk, Wv, Wo, wqb, wkb, wvb, wob);

    gemm_qkv<<<dim3(64, 6, 3), 256, 0, stream>>>(xb, wqb, wkb, wvb, bv, qb, kb, vtb);

    attn_kernel<<<dim3(8, NH, BATCH), 256, 0, stream>>>(qb, kb, vtb, eb, obuf);

    gemm_out<<<dim3(64, 6), 256, 0, stream>>>(obuf, wob, bo, out);
}

// Round 3
// 220.284 us; speedup vs baseline: 1.1555x; 1.0458x over previous
//
#include <hip/hip_runtime.h>
#include <stdint.h>

typedef unsigned short u16;
typedef unsigned int u32;
typedef __bf16 bf16x8 __attribute__((ext_vector_type(8)));
typedef float f32x4 __attribute__((ext_vector_type(4)));

#define NH 12
#define HD 64
#define SEQ 512
#define BATCH 16
#define HID 768
#define SCALE_Q 0.03608439182435161f  // 768^-0.5

__device__ __forceinline__ u16 f2bf(float f) {
    u32 u = __builtin_bit_cast(u32, f);
    u32 r = (u + 0x7FFFu + ((u >> 16) & 1u)) >> 16;
    return (u16)r;
}
__device__ __forceinline__ float bf2f(u16 h) {
    return __builtin_bit_cast(float, (u32)h << 16);
}

// async global -> LDS, 16B per lane; lds dest = wave-uniform base + lane*16
__device__ __forceinline__ void gl2lds16(const u16* g, u16* lds_base) {
    __builtin_amdgcn_global_load_lds(
        (const __attribute__((address_space(1))) u32*)g,
        (__attribute__((address_space(3))) u32*)lds_base, 16, 0, 0);
}

// ---------------- fp32 -> bf16 converts ----------------
__global__ void cvt_kernel(const float* __restrict__ src, u16* __restrict__ dst) {
    int i = (blockIdx.x * 256 + threadIdx.x) * 4;
    float4 v = *(const float4*)(src + i);
    ushort4 o;
    o.x = f2bf(v.x); o.y = f2bf(v.y); o.z = f2bf(v.z); o.w = f2bf(v.w);
    *(ushort4*)(dst + i) = o;
}

__global__ void cvt4_kernel(const float* __restrict__ s0, const float* __restrict__ s1,
                            const float* __restrict__ s2, const float* __restrict__ s3,
                            u16* __restrict__ d0, u16* __restrict__ d1,
                            u16* __restrict__ d2, u16* __restrict__ d3) {
    int y = blockIdx.y;
    const float* s = (y == 0) ? s0 : (y == 1) ? s1 : (y == 2) ? s2 : s3;
    u16* d = (y == 0) ? d0 : (y == 1) ? d1 : (y == 2) ? d2 : d3;
    int i = (blockIdx.x * 256 + threadIdx.x) * 4;
    float4 v = *(const float4*)(s + i);
    ushort4 o;
    o.x = f2bf(v.x); o.y = f2bf(v.y); o.z = f2bf(v.z); o.w = f2bf(v.w);
    *(ushort4*)(d + i) = o;
}

// ---------------- m97-structure NT GEMM mainloop ----------------
__device__ __forceinline__ void gemm_mainloop(
    const u16* __restrict__ Ag, const u16* __restrict__ Bg,
    u16* As, u16* Bs, f32x4 (&acc)[4][4])
{
    const int tid = threadIdx.x;
    const int l = tid & 63, w = tid >> 6;
    const int wm = w & 1, wn = w >> 1;
    const int lr = l & 15, lg = l >> 4;

    const int c0 = tid, c1 = tid + 256;
    const int r0 = c0 >> 2, q0 = (c0 & 3) * 8;
    const int r1 = c1 >> 2, q1 = (c1 & 3) * 8;
    u16* Alds0 = As + w * 512;
    u16* Alds1 = As + 2048 + w * 512;
    u16* Blds0 = Bs + w * 512;
    u16* Blds1 = Bs + 2048 + w * 512;

    for (int k0 = 0; k0 < HID; k0 += 32) {
        __syncthreads();
        gl2lds16(Ag + (size_t)r0 * HID + k0 + q0, Alds0);
        gl2lds16(Ag + (size_t)r1 * HID + k0 + q1, Alds1);
        gl2lds16(Bg + (size_t)r0 * HID + k0 + q0, Blds0);
        gl2lds16(Bg + (size_t)r1 * HID + k0 + q1, Blds1);
        __syncthreads();

        bf16x8 af[4], bfr[4];
#pragma unroll
        for (int mi = 0; mi < 4; mi++)
            af[mi] = *(const bf16x8*)(As + (wm * 64 + mi * 16 + lr) * 32 + lg * 8);
#pragma unroll
        for (int ni = 0; ni < 4; ni++)
            bfr[ni] = *(const bf16x8*)(Bs + (wn * 64 + ni * 16 + lr) * 32 + lg * 8);
#pragma unroll
        for (int mi = 0; mi < 4; mi++)
#pragma unroll
            for (int ni = 0; ni < 4; ni++)
                acc[mi][ni] = __builtin_amdgcn_mfma_f32_16x16x32_bf16(af[mi], bfr[ni], acc[mi][ni], 0, 0, 0);
    }
}

// ---------------- fused QKV GEMM ----------------
__global__ __launch_bounds__(256, 3) void gemm_qkv(
    const u16* __restrict__ xb, const u16* __restrict__ wq,
    const u16* __restrict__ wk, const u16* __restrict__ wv,
    const float* __restrict__ bv,
    u16* __restrict__ qb, u16* __restrict__ kb, u16* __restrict__ vtb)
{
    __shared__ __align__(16) u16 As[128 * 32];
    __shared__ __align__(16) u16 Bs[128 * 32];
    const int tid = threadIdx.x;
    const int l = tid & 63, w = tid >> 6;
    const int wm = w & 1, wn = w >> 1;
    const int lr = l & 15, lg = l >> 4;
    const int mt = blockIdx.x, nt = blockIdx.y, z = blockIdx.z;

    const u16* Bw = (z == 0) ? wq : (z == 1) ? wk : wv;
    const u16* Ag = xb + (size_t)(mt * 128) * HID;
    const u16* Bg = Bw + (size_t)(nt * 128) * HID;

    f32x4 acc[4][4] = {};
    gemm_mainloop(Ag, Bg, As, Bs, acc);

    const float sc = (z == 0) ? SCALE_Q : 1.0f;  // fold 768^-0.5 into Q
#pragma unroll
    for (int mi = 0; mi < 4; mi++) {
#pragma unroll
        for (int ni = 0; ni < 4; ni++) {
            const int jg = nt * 128 + wn * 64 + ni * 16 + lr;
            const int h = jg >> 6, d = jg & 63;
            if (z < 2) {
                u16* O = (z == 0) ? qb : kb;  // [b,h,n,d]
#pragma unroll
                for (int r = 0; r < 4; r++) {
                    int ig = mt * 128 + wm * 64 + mi * 16 + lg * 4 + r;
                    int b = ig >> 9, n = ig & 511;
                    O[((size_t)(b * NH + h) * SEQ + n) * HD + d] = f2bf(acc[mi][ni][r] * sc);
                }
            } else {                           // v: [b,h,d,m] transposed, + bias
                float bb = bv[jg];
                int i0 = mt * 128 + wm * 64 + mi * 16 + lg * 4;
                int b = i0 >> 9, m = i0 & 511;
                ushort4 pk;
                pk.x = f2bf(acc[mi][ni][0] + bb);
                pk.y = f2bf(acc[mi][ni][1] + bb);
                pk.z = f2bf(acc[mi][ni][2] + bb);
                pk.w = f2bf(acc[mi][ni][3] + bb);
                *(ushort4*)(vtb + ((size_t)(b * NH + h) * HD + d) * SEQ + m) = pk;
            }
        }
    }
}

// ---------------- output GEMM: fp32 out + bias ----------------
__global__ __launch_bounds__(256, 3) void gemm_out(
    const u16* __restrict__ A, const u16* __restrict__ wo,
    const float* __restrict__ bo, float* __restrict__ Cout)
{
    __shared__ __align__(16) u16 As[128 * 32];
    __shared__ __align__(16) u16 Bs[128 * 32];
    const int tid = threadIdx.x;
    const int l = tid & 63, w = tid >> 6;
    const int wm = w & 1, wn = w >> 1;
    const int lr = l & 15, lg = l >> 4;
    const int mt = blockIdx.x, nt = blockIdx.y;

    const u16* Ag = A + (size_t)(mt * 128) * HID;
    const u16* Bg = wo + (size_t)(nt * 128) * HID;

    f32x4 acc[4][4] = {};
    gemm_mainloop(Ag, Bg, As, Bs, acc);

#pragma unroll
    for (int mi = 0; mi < 4; mi++) {
#pragma unroll
        for (int ni = 0; ni < 4; ni++) {
            const int jg = nt * 128 + wn * 64 + ni * 16 + lr;
            float bb = bo[jg];
#pragma unroll
            for (int r = 0; r < 4; r++) {
                int ig = mt * 128 + wm * 64 + mi * 16 + lg * 4 + r;
                Cout[(size_t)ig * HID + jg] = acc[mi][ni][r] + bb;
            }
        }
    }
}

// ---------------- fused flash attention ----------------
// K/V tiles: unpadded [64][64] bf16, XOR-swizzled (16B chunk c stored at c^(row&7)),
// staged via global_load_lds. bias (bf16) preloaded as MFMA C-init. 4 blocks/CU.
#define LDA 88

__global__ __launch_bounds__(256, 4) void attn_kernel(
    const u16* __restrict__ qb, const u16* __restrict__ kb, const u16* __restrict__ vtb,
    const u16* __restrict__ ebb, u16* __restrict__ ob)
{
    __shared__ __align__(16) u16 Ks[64 * 64];
    __shared__ __align__(16) u16 Vs[64 * 64];
    __shared__ __align__(16) u16 Ps[4][16 * LDA];

    const int tid = threadIdx.x;
    const int l = tid & 63, w = tid >> 6;
    const int lr = l & 15, lg = l >> 4;
    const int qt = blockIdx.x, h = blockIdx.y, b = blockIdx.z;
    const int bh = b * NH + h;
    const int qrow0 = qt * 64 + w * 16;

    // Q fragments (A-layout, pre-scaled by SCALE_Q), resident all kernel
    const u16* qptr = qb + ((size_t)bh * SEQ + qrow0 + lr) * HD;
    bf16x8 qf0 = *(const bf16x8*)(qptr + lg * 8);
    bf16x8 qf1 = *(const bf16x8*)(qptr + 32 + lg * 8);

    const u16* Kg = kb + (size_t)bh * SEQ * HD;
    const u16* Vg = vtb + (size_t)bh * HD * SEQ;
    const u16* Eg = ebb + ((size_t)b * SEQ + qrow0 + lg * 4) * SEQ;

    f32x4 oacc[4] = {};
    float run_m[4] = {-1e30f, -1e30f, -1e30f, -1e30f};
    float run_l[4] = {0.f, 0.f, 0.f, 0.f};
    int nzf[4] = {0, 0, 0, 0};

    // staging chunks: p = row*8 + c', c' = c ^ (row&7); this thread handles p0/p1
    const int p0 = tid, p1 = tid + 256;
    const int kr0 = p0 >> 3, kc0 = (p0 & 7) ^ (kr0 & 7);
    const int kr1 = p1 >> 3, kc1 = (p1 & 7) ^ (kr1 & 7);
    u16* Ks0 = Ks + w * 512;           // wave w's chunk group (64 chunks = 1 KiB)
    u16* Ks1 = Ks + 2048 + w * 512;
    u16* Vs0 = Vs + w * 512;
    u16* Vs1 = Vs + 2048 + w * 512;

    for (int mt0 = 0; mt0 < SEQ; mt0 += 64) {
        // bias tile preload (bf16, C-fragment layout) — overlaps K/V staging
        u16 bl[4][4];
#pragma unroll
        for (int mi = 0; mi < 4; mi++)
#pragma unroll
            for (int r = 0; r < 4; r++)
                bl[mi][r] = Eg[(size_t)r * SEQ + mt0 + mi * 16 + lr];

        __syncthreads();  // prev tile's ds_reads done
        gl2lds16(Kg + (size_t)(mt0 + kr0) * HD + kc0 * 8, Ks0);
        gl2lds16(Kg + (size_t)(mt0 + kr1) * HD + kc1 * 8, Ks1);
        gl2lds16(Vg + (size_t)kr0 * SEQ + mt0 + kc0 * 8, Vs0);
        gl2lds16(Vg + (size_t)kr1 * SEQ + mt0 + kc1 * 8, Vs1);
        __syncthreads();  // drains vmcnt -> tiles complete

        // S = (Q*scale) K^T + bias via C-init
        float sm[4][4];
#pragma unroll
        for (int mi = 0; mi < 4; mi++) {
            const int row = mi * 16 + lr;
            bf16x8 kf0 = *(const bf16x8*)(Ks + row * 64 + ((lg ^ (row & 7)) * 8));
            bf16x8 kf1 = *(const bf16x8*)(Ks + row * 64 + (((4 + lg) ^ (row & 7)) * 8));
            f32x4 s;
#pragma unroll
            for (int r = 0; r < 4; r++) s[r] = bf2f(bl[mi][r]);
            s = __builtin_amdgcn_mfma_f32_16x16x32_bf16(qf0, kf0, s, 0, 0, 0);
            s = __builtin_amdgcn_mfma_f32_16x16x32_bf16(qf1, kf1, s, 0, 0, 0);
#pragma unroll
            for (int r = 0; r < 4; r++) {
                float sv = s[r];
                nzf[r] |= (sv != 0.0f);
                sm[mi][r] = sv;
            }
        }

        // online softmax (row state replicated across the 16-lane col group)
        u16* Pw = Ps[w];
#pragma unroll
        for (int r = 0; r < 4; r++) {
            float tm = fmaxf(fmaxf(sm[0][r], sm[1][r]), fmaxf(sm[2][r], sm[3][r]));
            tm = fmaxf(tm, __shfl_xor(tm, 1));
            tm = fmaxf(tm, __shfl_xor(tm, 2));
            tm = fmaxf(tm, __shfl_xor(tm, 4));
            tm = fmaxf(tm, __shfl_xor(tm, 8));
            float nm = fmaxf(run_m[r], tm);
            float alpha = __expf(run_m[r] - nm);
            run_m[r] = nm;
            float ps = 0.f;
#pragma unroll
            for (int mi = 0; mi < 4; mi++) {
                float p = __expf(sm[mi][r] - nm);
                sm[mi][r] = p;
                ps += p;
            }
            ps += __shfl_xor(ps, 1);
            ps += __shfl_xor(ps, 2);
            ps += __shfl_xor(ps, 4);
            ps += __shfl_xor(ps, 8);
            run_l[r] = run_l[r] * alpha + ps;
#pragma unroll
            for (int di = 0; di < 4; di++) oacc[di][r] *= alpha;
        }
        // P: C-layout -> per-wave LDS -> A-layout
#pragma unroll
        for (int mi = 0; mi < 4; mi++)
#pragma unroll
            for (int r = 0; r < 4; r++)
                Pw[(lg * 4 + r) * LDA + mi * 16 + lr] = f2bf(sm[mi][r]);

#pragma unroll
        for (int ks = 0; ks < 2; ks++) {
            bf16x8 pf = *(const bf16x8*)(Pw + lr * LDA + ks * 32 + lg * 8);
#pragma unroll
            for (int di = 0; di < 4; di++) {
                const int row = di * 16 + lr;
                bf16x8 vf = *(const bf16x8*)(Vs + row * 64 + (((ks * 4 + lg) ^ (row & 7)) * 8));
                oacc[di] = __builtin_amdgcn_mfma_f32_16x16x32_bf16(pf, vf, oacc[di], 0, 0, 0);
            }
        }
    }

#pragma unroll
    for (int r = 0; r < 4; r++) {
        int nz = nzf[r];
        nz |= __shfl_xor(nz, 1);
        nz |= __shfl_xor(nz, 2);
        nz |= __shfl_xor(nz, 4);
        nz |= __shfl_xor(nz, 8);
        float inv = nz ? (1.0f / run_l[r]) : 0.0f;  // all-zero row -> 0 (ref: NaN->0)
        int n = qrow0 + lg * 4 + r;
        u16* orow = ob + ((size_t)b * SEQ + n) * HID + h * HD;
#pragma unroll
        for (int di = 0; di < 4; di++)
            orow[di * 16 + lr] = f2bf(oacc[di][r] * inv);
    }
}

// ---------------- launch ----------------
extern "C" void kernel_launch(void* const* d_in, const int* in_sizes, int n_in,
                              void* d_out, int out_size, void* d_ws, size_t ws_size,
                              hipStream_t stream) {
    (void)in_sizes; (void)n_in; (void)out_size; (void)ws_size;
    const float* x  = (const float*)d_in[0];
    const float* eb = (const float*)d_in[1];
    const float* Wq = (const float*)d_in[2];
    const float* Wk = (const float*)d_in[3];
    const float* Wv = (const float*)d_in[4];
    const float* bv = (const float*)d_in[5];
    const float* Wo = (const float*)d_in[6];
    const float* bo = (const float*)d_in[7];
    float* out = (float*)d_out;

    const int NX = BATCH * SEQ * HID;   // 6291456
    const int NW = HID * HID;           // 589824
    const int NE = BATCH * SEQ * SEQ;   // 4194304
    u16* ws   = (u16*)d_ws;
    u16* xb   = ws;
    u16* wqb  = xb + NX;
    u16* wkb  = wqb + NW;
    u16* wvb  = wkb + NW;
    u16* wob  = wvb + NW;
    u16* qb   = wob + NW;
    u16* kb   = qb + NX;
    u16* vtb  = kb + NX;
    u16* obuf = vtb + NX;
    u16* ebb  = obuf + NX;

    cvt_kernel<<<NX / 1024, 256, 0, stream>>>(x, xb);
    cvt_kernel<<<NE / 1024, 256, 0, stream>>>(eb, ebb);
    cvt4_kernel<<<dim3(NW / 1024, 4), 256, 0, stream>>>(Wq, Wk, Wv, Wo, wqb, wkb, wvb, wob);

    gemm_qkv<<<dim3(64, 6, 3), 256, 0, stream>>>(xb, wqb, wkb, wvb, bv, qb, kb, vtb);

    attn_kernel<<<dim3(8, NH, BATCH), 256, 0, stream>>>(qb, kb, vtb, ebb, obuf);

    gemm_out<<<dim3(64, 6), 256, 0, stream>>>(obuf, wob, bo, out);
}